// Round 5
// baseline (68.765 us; speedup 1.0000x reference)
//
#include <hip/hip_runtime.h>
#include <cstddef>

constexpr int NGF    = 80;
constexpr int TLEN   = 1000;
constexpr int SPLICE = 10;
constexpr int PATCH  = 2 * SPLICE + 1;  // 21
constexpr int NH     = 50;
constexpr int TC     = 25;              // t per block
constexpr int SW     = 57;              // seg row stride (odd -> <=2-way LDS aliasing)
constexpr float NL2E = -1.44269504088896341f;

typedef __attribute__((ext_vector_type(8))) short  short8;
typedef __attribute__((ext_vector_type(4))) float  f32x4;

__device__ __forceinline__ float fast_sigmoid(float a) {
    float e = __builtin_amdgcn_exp2f(a * NL2E);
    return __builtin_amdgcn_rcpf(1.0f + e);
}

__device__ __forceinline__ unsigned short f32_to_bf16(float f) {
    unsigned int u = __builtin_bit_cast(unsigned int, f);
    u += 0x7fffu + ((u >> 16) & 1u);   // RNE
    return (unsigned short)(u >> 16);
}

__global__ __launch_bounds__(256) void relevance_mfma(
    const float* __restrict__ x,    // [B, NGF, TLEN]
    const float* __restrict__ W1,   // [NH, PATCH]
    const float* __restrict__ b1,   // [NH]
    const float* __restrict__ W2,   // [NH]
    const float* __restrict__ b2,   // [1]
    float* __restrict__ out)        // [B, TLEN, NGF]
{
    const int tid  = threadIdx.x;
    const int wave = tid >> 6;
    const int lane = tid & 63;
    const int q    = lane >> 4;
    const int jj   = lane & 15;
    const int t0   = blockIdx.x * TC;
    const int b    = blockIdx.y;

    __shared__ float seg[NGF * SW];     // seg[f][c] = xpad[b][f][t0+c]
    __shared__ float zbuf[TC * NGF];    // [t][f], coalesced dump at end

    // ---- stage x region (zero-padded)
    const float* xb = x + (size_t)b * NGF * TLEN;
    for (int i = tid; i < NGF * SW; i += 256) {
        const unsigned f = (unsigned)i / SW;
        const int c = i - (int)f * SW;
        const int gx = t0 + c - SPLICE;
        seg[i] = (gx >= 0 && gx < TLEN) ? xb[f * TLEN + gx] : 0.0f;
    }

    // ---- B fragments: W1^T scaled by -log2(e); k-slot k = 8q+e (same map as A)
    union FragU { unsigned short us[8]; short8 s8; };
    FragU bf0, bf1, bf2, bf3;
    float b1s[4], w2v[4];
#define BUILD_FRAG(N, DST)                                                  \
    {                                                                       \
        const int j = jj + 16 * N;                                          \
        _Pragma("unroll")                                                   \
        for (int e = 0; e < 8; ++e) {                                       \
            const int k = 8 * q + e;                                        \
            const float w = (j < NH && k < PATCH) ? W1[j * PATCH + k] : 0.f;\
            DST.us[e] = f32_to_bf16(NL2E * w);                              \
        }                                                                   \
        b1s[N] = (j < NH) ? NL2E * b1[j] : 0.0f;                            \
        w2v[N] = (j < NH) ? W2[j] : 0.0f;                                   \
    }
    BUILD_FRAG(0, bf0) BUILD_FRAG(1, bf1) BUILD_FRAG(2, bf2) BUILD_FRAG(3, bf3)
#undef BUILD_FRAG
    const float b2v = b2[0];

    __syncthreads();

    // ---- tiles: (fc, tt), fc in [0,5) f-chunk of 16, tt in [0,TC)
    for (int tile = wave; tile < 5 * TC; tile += 4) {
        const unsigned tt = (unsigned)tile / 5u;
        const int fc = tile - (int)tt * 5;
        const int f0 = fc * 16;

        // A[r=jj][k=8q+e] = seg[f0+jj][tt + 8q + e]
        const float* sp = &seg[(f0 + jj) * SW + (int)tt + 8 * q];
        const float p0 = sp[0], p1 = sp[1], p2 = sp[2], p3 = sp[3];
        const float p4 = sp[4], p5 = sp[5], p6 = sp[6], p7 = sp[7];

        int a0, a1, a2, a3;
        asm("v_cvt_pk_bf16_f32 %0, %1, %2" : "=v"(a0) : "v"(p0), "v"(p1));
        asm("v_cvt_pk_bf16_f32 %0, %1, %2" : "=v"(a1) : "v"(p2), "v"(p3));
        asm("v_cvt_pk_bf16_f32 %0, %1, %2" : "=v"(a2) : "v"(p4), "v"(p5));
        asm("v_cvt_pk_bf16_f32 %0, %1, %2" : "=v"(a3) : "v"(p6), "v"(p7));
        union { int i[4]; short8 s8; } af;
        af.i[0] = a0; af.i[1] = a1; af.i[2] = a2; af.i[3] = a3;

        // bias via C-in (acc already holds -log2e * preact bias)
        f32x4 acc0 = {b1s[0], b1s[0], b1s[0], b1s[0]};
        f32x4 acc1 = {b1s[1], b1s[1], b1s[1], b1s[1]};
        f32x4 acc2 = {b1s[2], b1s[2], b1s[2], b1s[2]};
        f32x4 acc3 = {b1s[3], b1s[3], b1s[3], b1s[3]};
        acc0 = __builtin_amdgcn_mfma_f32_16x16x32_bf16(af.s8, bf0.s8, acc0, 0, 0, 0);
        acc1 = __builtin_amdgcn_mfma_f32_16x16x32_bf16(af.s8, bf1.s8, acc1, 0, 0, 0);
        acc2 = __builtin_amdgcn_mfma_f32_16x16x32_bf16(af.s8, bf2.s8, acc2, 0, 0, 0);
        acc3 = __builtin_amdgcn_mfma_f32_16x16x32_bf16(af.s8, bf3.s8, acc3, 0, 0, 0);

        // h = rcp(1 + exp2(acc)); z_r = sum_n w2v[n]*h  (acc = -log2e*preact)
        float z0 = 0.f, z1 = 0.f, z2 = 0.f, z3 = 0.f;
#define EPI(ACC, N)                                                          \
        z0 = fmaf(w2v[N], __builtin_amdgcn_rcpf(1.0f + __builtin_amdgcn_exp2f(ACC[0])), z0); \
        z1 = fmaf(w2v[N], __builtin_amdgcn_rcpf(1.0f + __builtin_amdgcn_exp2f(ACC[1])), z1); \
        z2 = fmaf(w2v[N], __builtin_amdgcn_rcpf(1.0f + __builtin_amdgcn_exp2f(ACC[2])), z2); \
        z3 = fmaf(w2v[N], __builtin_amdgcn_rcpf(1.0f + __builtin_amdgcn_exp2f(ACC[3])), z3);
        EPI(acc0, 0) EPI(acc1, 1) EPI(acc2, 2) EPI(acc3, 3)
#undef EPI

        #pragma unroll
        for (int m = 1; m < 16; m <<= 1) {
            z0 += __shfl_xor(z0, m, 16);
            z1 += __shfl_xor(z1, m, 16);
            z2 += __shfl_xor(z2, m, 16);
            z3 += __shfl_xor(z3, m, 16);
        }
        if (jj < 4) {
            const float zv = jj == 0 ? z0 : jj == 1 ? z1 : jj == 2 ? z2 : z3;
            zbuf[(int)tt * NGF + f0 + 4 * q + jj] = fast_sigmoid(zv + b2v);
        }
    }

    __syncthreads();

    // ---- coalesced dump: out[b][t0..t0+TC)[*] contiguous = TC*NGF floats
    float* ob = out + ((size_t)b * TLEN + t0) * NGF;
    const f32x4* zb4 = (const f32x4*)zbuf;
    f32x4* ob4 = (f32x4*)ob;
    for (int i = tid; i < TC * NGF / 4; i += 256)
        ob4[i] = zb4[i];
}

extern "C" void kernel_launch(void* const* d_in, const int* in_sizes, int n_in,
                              void* d_out, int out_size, void* d_ws, size_t ws_size,
                              hipStream_t stream) {
    const float* x  = (const float*)d_in[0];
    const float* W1 = (const float*)d_in[1];
    const float* b1 = (const float*)d_in[2];
    const float* W2 = (const float*)d_in[3];
    const float* b2 = (const float*)d_in[4];
    float* out = (float*)d_out;

    const int B = in_sizes[0] / (NGF * TLEN);  // 32

    dim3 grid(TLEN / TC, B);                   // (40, 32) = 1280 blocks
    relevance_mfma<<<grid, 256, 0, stream>>>(x, W1, b1, W2, b2, out);
}